// Round 5
// baseline (19042.006 us; speedup 1.0000x reference)
//
#include <hip/hip_runtime.h>
#include <hip/hip_bf16.h>
#include <math.h>

namespace {

constexpr int N = 20000;
constexpr int E = 320000;
constexpr int C = 32;
constexpr int S = 9;
constexpr int Z = 10;
constexpr int G = 16;
constexpr int NB = 8;
constexpr int H = 64;
constexpr int CS = C * S;          // 288
constexpr float RMAX = 5.0f;
constexpr float PI_F = 3.14159265358979323846f;
constexpr float C1 = 1.7320508075688772f;   // sqrt(3)
constexpr float C2 = 3.8729833462074170f;   // sqrt(15)
constexpr float C3 = 1.1180339887498949f;   // sqrt(5)/2
constexpr float BESS_A = 0.6324555320336759f; // sqrt(2/5)

__device__ __forceinline__ float sigm(float x) { return 1.0f / (1.0f + __expf(-x)); }

// ---------------- node-level kernels ----------------

__global__ void k_node_init(const float* __restrict__ attrs, const float* __restrict__ ae,
                            const float* __restrict__ Wemb, const int* __restrict__ batch,
                            int* __restrict__ sp_out, float* __restrict__ ne0,
                            float* __restrict__ h0, float* __restrict__ e0g) {
    int n = blockIdx.x * blockDim.x + threadIdx.x;
    if (n >= N) return;
    int sp = 0;
#pragma unroll
    for (int z = 0; z < Z; ++z)
        if (attrs[n * Z + z] > 0.5f) sp = z;
    sp_out[n] = sp;
    float e = ae[sp];
    ne0[n] = e;
    atomicAdd(&e0g[batch[n]], e);
#pragma unroll
    for (int c = 0; c < C; ++c) h0[n * C + c] = Wemb[sp * C + c];
}

__global__ void k_matmul_CC(const float* __restrict__ hin, const float* __restrict__ W,
                            float* __restrict__ hout) {
    int t = blockIdx.x * blockDim.x + threadIdx.x;
    if (t >= N * C) return;
    int n = t / C, d = t % C;
    float acc = 0.f;
#pragma unroll
    for (int c = 0; c < C; ++c) acc += hin[n * C + c] * W[c * C + d];
    hout[t] = acc;
}

__global__ void k_msg(const float* __restrict__ msum, const float* __restrict__ Wlin,
                      float* __restrict__ msg) {
    int t = blockIdx.x * blockDim.x + threadIdx.x;
    if (t >= N * C) return;
    int n = t / C, d = t % C;
    float acc = 0.f;
    for (int k = 0; k < CS; ++k) acc += msum[(size_t)n * CS + k] * Wlin[k * C + d];
    msg[t] = acc * (1.0f / 16.0f);
}

template <int WRITE_H>
__global__ void k_node_h(const float* __restrict__ msg, const float* __restrict__ hin,
                         const int* __restrict__ sp_arr, const float* __restrict__ Wprod,
                         const float* __restrict__ Wskip, const float* __restrict__ Wread,
                         float* __restrict__ hout_ws, float* __restrict__ es,
                         float* __restrict__ feats_out) {
    int n = blockIdx.x * blockDim.x + threadIdx.x;
    if (n >= N) return;
    int sp = sp_arr[n];
    float m[C], hi[C];
#pragma unroll
    for (int c = 0; c < C; ++c) { m[c] = msg[n * C + c]; hi[c] = hin[n * C + c]; }
    const float* Wsk = Wskip + (size_t)sp * C * C;
    float esum = 0.f;
    for (int d = 0; d < C; ++d) {
        float acc = 0.f;
#pragma unroll
        for (int c = 0; c < C; ++c) acc += m[c] * Wprod[c * C + d] + hi[c] * Wsk[c * C + d];
        esum += acc * Wread[d];
        if constexpr (WRITE_H) hout_ws[n * C + d] = acc;
        feats_out[(size_t)n * (2 * C) + d] = acc;
    }
    es[n] += esum;
}

__global__ void k_finalize(const float* __restrict__ ne0, const float* __restrict__ es,
                           const float* __restrict__ scale_p, const float* __restrict__ shift_p,
                           const int* __restrict__ batch, float* __restrict__ node_energy_out,
                           float* __restrict__ ieg) {
    int n = blockIdx.x * blockDim.x + threadIdx.x;
    if (n >= N) return;
    float nies = scale_p[0] * es[n] + shift_p[0];
    node_energy_out[n] = ne0[n] + nies;
    atomicAdd(&ieg[batch[n]], nies);
}

__global__ void k_graph(const float* __restrict__ e0g, const float* __restrict__ ieg,
                        float* __restrict__ tot_out, float* __restrict__ inter_out) {
    int g = threadIdx.x;
    if (g < G) { tot_out[g] = e0g[g] + ieg[g]; inter_out[g] = ieg[g]; }
}

__global__ void k_const1(const float* __restrict__ Wr1, const float* __restrict__ Wprod1,
                         const float* __restrict__ Wlin1, const float* __restrict__ Wskip1,
                         const float* __restrict__ scale_p, float* __restrict__ gms1,
                         float* __restrict__ gskip1) {
    int t = threadIdx.x;
    float sc = scale_p[0];
    if (t < CS) {
        float acc = 0.f;
        for (int d = 0; d < C; ++d) {
            float gm = 0.f;
#pragma unroll
            for (int d2 = 0; d2 < C; ++d2) gm += Wr1[d2] * Wprod1[d * C + d2];
            acc += gm * Wlin1[t * C + d];
        }
        gms1[t] = sc * acc * (1.0f / 16.0f);
    }
    if (t < Z * C) {
        int z = t / C, c = t % C;
        float acc = 0.f;
#pragma unroll
        for (int d = 0; d < C; ++d) acc += Wskip1[(z * C + c) * C + d] * Wr1[d];
        gskip1[t] = sc * acc;
    }
}

__global__ void k_gh1(const float* __restrict__ Wr0, const float* __restrict__ gskip1,
                      const int* __restrict__ sp_arr, const float* __restrict__ ghu1,
                      const float* __restrict__ Wup1, const float* __restrict__ scale_p,
                      float* __restrict__ gh1) {
    int t = blockIdx.x * blockDim.x + threadIdx.x;
    if (t >= N * C) return;
    int n = t / C, c = t % C;
    float acc = scale_p[0] * Wr0[c] + gskip1[sp_arr[n] * C + c];
#pragma unroll
    for (int d = 0; d < C; ++d) acc += ghu1[n * C + d] * Wup1[c * C + d];
    gh1[t] = acc;
}

__global__ void k_gmsg(const float* __restrict__ gh, const float* __restrict__ Wprod,
                       float* __restrict__ gmsg) {
    int t = blockIdx.x * blockDim.x + threadIdx.x;
    if (t >= N * C) return;
    int n = t / C, d = t % C;
    float acc = 0.f;
#pragma unroll
    for (int d2 = 0; d2 < C; ++d2) acc += gh[n * C + d2] * Wprod[d * C + d2];
    gmsg[t] = acc;
}

__global__ void k_gmsum(const float* __restrict__ gmsg, const float* __restrict__ Wlin,
                        float* __restrict__ gms) {
    int t = blockIdx.x * blockDim.x + threadIdx.x;
    if (t >= N * CS) return;
    int n = t / CS, k = t % CS;
    float acc = 0.f;
#pragma unroll
    for (int d = 0; d < C; ++d) acc += gmsg[n * C + d] * Wlin[k * C + d];
    gms[t] = acc * (1.0f / 16.0f);
}

// ---------------- CSR build (receiver-sorted) ----------------

__global__ void k_csr_count(const int* __restrict__ eidx, int* __restrict__ cnt) {
    int e = blockIdx.x * 256 + threadIdx.x;
    if (e >= E) return;
    atomicAdd(&cnt[eidx[E + e]], 1);
}

__global__ __launch_bounds__(1024) void k_csr_scan(const int* __restrict__ cnt,
                                                   int* __restrict__ rowstart,
                                                   int* __restrict__ pos) {
    __shared__ int part[1024];
    int t = threadIdx.x;
    const int CHUNK = 20;   // 1024*20 >= N
    int base = t * CHUNK;
    int sum = 0;
    for (int i = 0; i < CHUNK; ++i) {
        int idx = base + i;
        if (idx < N) sum += cnt[idx];
    }
    part[t] = sum;
    __syncthreads();
    for (int off = 1; off < 1024; off <<= 1) {
        int v = (t >= off) ? part[t - off] : 0;
        __syncthreads();
        if (t >= off) part[t] += v;
        __syncthreads();
    }
    int run = (t == 0) ? 0 : part[t - 1];
    for (int i = 0; i < CHUNK; ++i) {
        int idx = base + i;
        if (idx < N) { rowstart[idx] = run; pos[idx] = run; run += cnt[idx]; }
    }
    if (t == 1023) rowstart[N] = run;
}

__global__ void k_csr_fill(const int* __restrict__ eidx, int* __restrict__ pos,
                           int* __restrict__ perm) {
    int e = blockIdx.x * 256 + threadIdx.x;
    if (e >= E) return;
    int slot = atomicAdd(&pos[eidx[E + e]], 1);
    perm[slot] = e;
}

// ---------------- edge pipeline ----------------

__global__ __launch_bounds__(256) void k_geom(
    const float* __restrict__ pos, const float* __restrict__ shifts,
    const int* __restrict__ eidx, float* __restrict__ Yt, float* __restrict__ EFt) {
    int e = blockIdx.x * 256 + threadIdx.x;
    int snd = eidx[e], rcv = eidx[E + e];
    float vx = pos[rcv * 3 + 0] - pos[snd * 3 + 0] + shifts[e * 3 + 0];
    float vy = pos[rcv * 3 + 1] - pos[snd * 3 + 1] + shifts[e * 3 + 1];
    float vz = pos[rcv * 3 + 2] - pos[snd * 3 + 2] + shifts[e * 3 + 2];
    float r = sqrtf(vx * vx + vy * vy + vz * vz + 1e-12f);
    float inv = 1.0f / r;
    float x = vx * inv, y = vy * inv, z = vz * inv;
    Yt[0 * E + e] = 1.f;
    Yt[1 * E + e] = C1 * x;
    Yt[2 * E + e] = C1 * y;
    Yt[3 * E + e] = C1 * z;
    Yt[4 * E + e] = C2 * x * y;
    Yt[5 * E + e] = C2 * y * z;
    Yt[6 * E + e] = C3 * (3.f * z * z - 1.f);
    Yt[7 * E + e] = C2 * x * z;
    Yt[8 * E + e] = 0.5f * C2 * (x * x - y * y);
    float ru = r * (1.0f / RMAX);
    float env = 0.f;
    if (ru < 1.f) {
        float u2 = ru * ru, u4 = u2 * u2, u6 = u4 * u2, u7 = u6 * ru, u8 = u7 * ru;
        env = 1.f - 28.f * u6 + 48.f * u7 - 21.f * u8;
    }
#pragma unroll
    for (int b = 0; b < NB; ++b) {
        float kb = (b + 1) * (PI_F / RMAX);
        EFt[b * E + e] = BESS_A * __sinf(kb * r) * inv * env;
    }
}

// T2E (E x H edge-major), Z2^T (H x E k-major, bf16 pre-activation)
__global__ __launch_bounds__(256) void k_mlp_fwd(
    const float* __restrict__ EFt, const float* __restrict__ Wm1,
    const float* __restrict__ Wm2, float* __restrict__ T2E,
    __hip_bfloat16* __restrict__ Z2T) {
    __shared__ float w1[NB * H];
    __shared__ alignas(16) float w2t[H * H];   // transposed: [k][j]
    int tid = threadIdx.x;
    for (int i = tid; i < NB * H; i += 256) w1[i] = Wm1[i];
    for (int i = tid; i < H * H; i += 256) { int k = i >> 6, j = i & 63; w2t[i] = Wm2[j * H + k]; }
    __syncthreads();
    int e = blockIdx.x * 256 + tid;
    float ef[NB];
#pragma unroll
    for (int b = 0; b < NB; ++b) ef[b] = EFt[b * E + e];
    float t1[H];
#pragma unroll
    for (int j = 0; j < H; ++j) {
        float zz = 0.f;
#pragma unroll
        for (int b = 0; b < NB; ++b) zz += ef[b] * w1[b * H + j];
        t1[j] = zz * sigm(zz);
    }
    for (int k = 0; k < H; ++k) {
        float s0 = 0.f, s1 = 0.f, s2 = 0.f, s3 = 0.f;
#pragma unroll
        for (int jj = 0; jj < 16; ++jj) {
            float4 w = *reinterpret_cast<const float4*>(&w2t[k * H + jj * 4]);
            s0 += t1[jj * 4 + 0] * w.x;
            s1 += t1[jj * 4 + 1] * w.y;
            s2 += t1[jj * 4 + 2] * w.z;
            s3 += t1[jj * 4 + 3] * w.w;
        }
        float zz = (s0 + s1) + (s2 + s3);
        Z2T[(size_t)k * E + e] = __float2bfloat16(zz);
        T2E[(size_t)e * H + k] = zz * sigm(zz);
    }
}

// gather: wave per receiver node; msum[n,cs] = sum_{e in in(n)} hu[snd,c]*Y[s]*(t2 . W3[:,cs])
__global__ __launch_bounds__(1024) void k_gather(
    const int* __restrict__ eidx, const int* __restrict__ rowstart,
    const int* __restrict__ perm, const float* __restrict__ hu,
    const float* __restrict__ Wm3, const float* __restrict__ T2E,
    const float* __restrict__ Yt, float* __restrict__ msum) {
    __shared__ float w3[H * CS];   // 73.7 KB, native Wm3 layout [k][cs]
    int tid = threadIdx.x;
    for (int i = tid; i < H * CS; i += 1024) w3[i] = Wm3[i];
    __syncthreads();
    int wave = tid >> 6, lane = tid & 63;
    int n = blockIdx.x * 16 + wave;      // 1250 blocks * 16 waves = 20000 exact
    bool has4 = lane < 32;
    int cs4m = has4 ? lane + 256 : lane;
    const int ci0 = lane / 9,        si0 = lane % 9;
    const int ci1 = (lane + 64) / 9, si1 = (lane + 64) % 9;
    const int ci2 = (lane + 128) / 9, si2 = (lane + 128) % 9;
    const int ci3 = (lane + 192) / 9, si3 = (lane + 192) % 9;
    const int ci4 = cs4m / 9,        si4 = cs4m % 9;
    float acc0 = 0.f, acc1 = 0.f, acc2 = 0.f, acc3 = 0.f, acc4 = 0.f;
    int i0 = rowstart[n], i1 = rowstart[n + 1];
    for (int idx = i0; idx < i1; ++idx) {
        int e = perm[idx];
        int snd = eidx[e];
        float t2l = T2E[(size_t)e * H + lane];
        float yv0 = Yt[si0 * E + e], yv1 = Yt[si1 * E + e], yv2 = Yt[si2 * E + e],
              yv3 = Yt[si3 * E + e], yv4 = Yt[si4 * E + e];
        float hv0 = hu[snd * C + ci0], hv1 = hu[snd * C + ci1], hv2 = hu[snd * C + ci2],
              hv3 = hu[snd * C + ci3], hv4 = hu[snd * C + ci4];
        float d0 = 0.f, d1 = 0.f, d2 = 0.f, d3 = 0.f, d4 = 0.f;
#pragma unroll
        for (int k = 0; k < H; ++k) {
            float tv = __shfl(t2l, k, 64);
            d0 += tv * w3[k * CS + lane];
            d1 += tv * w3[k * CS + lane + 64];
            d2 += tv * w3[k * CS + lane + 128];
            d3 += tv * w3[k * CS + lane + 192];
            d4 += tv * w3[k * CS + cs4m];
        }
        acc0 += hv0 * yv0 * d0;
        acc1 += hv1 * yv1 * d1;
        acc2 += hv2 * yv2 * d2;
        acc3 += hv3 * yv3 * d3;
        acc4 += hv4 * yv4 * d4;
    }
    float* mrow = msum + (size_t)n * CS;
    mrow[lane] = acc0;
    mrow[lane + 64] = acc1;
    mrow[lane + 128] = acc2;
    mrow[lane + 192] = acc3;
    if (has4) mrow[lane + 256] = acc4;
}

// stage one 16-channel slice of Wm3 into LDS [cc][k][12]
__device__ __forceinline__ void stage_w3_half(float* w3t, const float* __restrict__ Wm3,
                                              int half, int tid) {
    for (int i = tid; i < 16 * H * S; i += 512) {
        int cc = i / (H * S), rem = i % (H * S), k = rem / S, s = rem % S;
        w3t[(cc * H + k) * 12 + s] = Wm3[k * CS + (half * 16 + cc) * S + s];
    }
}

// bwd part 1: recompute tpw; gY[s] = sum_c gm*hu*tpw; (L1) ghu[snd,c] += sum_s gm*Y*tpw
template <bool L1>
__global__ __launch_bounds__(512) void k_bwd1(
    const int* __restrict__ eidx, const float* __restrict__ hu,
    const float* __restrict__ Wm3, const float* __restrict__ T2E,
    const float* __restrict__ Yt, const float* __restrict__ gm,
    float* __restrict__ GY, float* __restrict__ ghu) {
    __shared__ alignas(16) float w3t[16 * H * 12];
    int tid = threadIdx.x;
    int e = blockIdx.x * 512 + tid;
    int snd = eidx[e], rcv = eidx[E + e];
    float t2r[H];
#pragma unroll
    for (int k4 = 0; k4 < H / 4; ++k4) {
        float4 v = *reinterpret_cast<const float4*>(&T2E[(size_t)e * H + k4 * 4]);
        t2r[k4 * 4 + 0] = v.x; t2r[k4 * 4 + 1] = v.y;
        t2r[k4 * 4 + 2] = v.z; t2r[k4 * 4 + 3] = v.w;
    }
    float yr[S];
#pragma unroll
    for (int s = 0; s < S; ++s) yr[s] = Yt[s * E + e];
    float gY[S];
#pragma unroll
    for (int s = 0; s < S; ++s) gY[s] = 0.f;
    for (int half = 0; half < 2; ++half) {
        __syncthreads();
        stage_w3_half(w3t, Wm3, half, tid);
        __syncthreads();
        for (int cc = 0; cc < 16; ++cc) {
            int c = half * 16 + cc;
            float hc = hu[snd * C + c];
            const float* gmc = L1 ? (gm + c * S) : (gm + (size_t)rcv * CS + c * S);
            float a[S];
#pragma unroll
            for (int s = 0; s < S; ++s) a[s] = 0.f;
            const float* w3c = &w3t[cc * H * 12];
#pragma unroll
            for (int k = 0; k < H; ++k) {
                float4 wa = *reinterpret_cast<const float4*>(w3c + k * 12);
                float4 wb = *reinterpret_cast<const float4*>(w3c + k * 12 + 4);
                float w8 = w3c[k * 12 + 8];
                float tv = t2r[k];
                a[0] += tv * wa.x; a[1] += tv * wa.y; a[2] += tv * wa.z; a[3] += tv * wa.w;
                a[4] += tv * wb.x; a[5] += tv * wb.y; a[6] += tv * wb.z; a[7] += tv * wb.w;
                a[8] += tv * w8;
            }
            float ghc = 0.f;
#pragma unroll
            for (int s = 0; s < S; ++s) {
                float gmv = gmc[s];
                gY[s] += gmv * hc * a[s];
                if (L1) ghc += gmv * yr[s] * a[s];
            }
            if (L1) atomicAdd(&ghu[snd * C + c], ghc);
        }
    }
#pragma unroll
    for (int s = 0; s < S; ++s) GY[s * E + e] = gY[s];
}

// bwd part 2: gt2[k] = sum_{c,s} (gm*hu*Y)[c,s] * Wm3[k,c,s]  -> GT2^T (H x E)
template <bool L1>
__global__ __launch_bounds__(512) void k_bwd2(
    const int* __restrict__ eidx, const float* __restrict__ hu,
    const float* __restrict__ Wm3, const float* __restrict__ Yt,
    const float* __restrict__ gm, float* __restrict__ GT2T) {
    __shared__ alignas(16) float w3t[16 * H * 12];
    int tid = threadIdx.x;
    int e = blockIdx.x * 512 + tid;
    int snd = eidx[e], rcv = eidx[E + e];
    float yr[S];
#pragma unroll
    for (int s = 0; s < S; ++s) yr[s] = Yt[s * E + e];
    float gt2[H];
#pragma unroll
    for (int k = 0; k < H; ++k) gt2[k] = 0.f;
    for (int half = 0; half < 2; ++half) {
        __syncthreads();
        stage_w3_half(w3t, Wm3, half, tid);
        __syncthreads();
        for (int cc = 0; cc < 16; ++cc) {
            int c = half * 16 + cc;
            float hc = hu[snd * C + c];
            const float* gmc = L1 ? (gm + c * S) : (gm + (size_t)rcv * CS + c * S);
            float gp[S];
#pragma unroll
            for (int s = 0; s < S; ++s) gp[s] = gmc[s] * hc * yr[s];
            const float* w3c = &w3t[cc * H * 12];
#pragma unroll
            for (int k = 0; k < H; ++k) {
                float4 wa = *reinterpret_cast<const float4*>(w3c + k * 12);
                float4 wb = *reinterpret_cast<const float4*>(w3c + k * 12 + 4);
                float w8 = w3c[k * 12 + 8];
                gt2[k] += gp[0] * wa.x + gp[1] * wa.y + gp[2] * wa.z + gp[3] * wa.w
                        + gp[4] * wb.x + gp[5] * wb.y + gp[6] * wb.z + gp[7] * wb.w
                        + gp[8] * w8;
            }
        }
    }
#pragma unroll
    for (int k = 0; k < H; ++k) GT2T[(size_t)k * E + e] = gt2[k];
}

// bwd MLP (streaming, via stored Z2) + geometry backward + force atomics
__global__ __launch_bounds__(256) void k_mlp_bwd(
    const float* __restrict__ pos, const float* __restrict__ shifts,
    const int* __restrict__ eidx, const float* __restrict__ EFt,
    const __hip_bfloat16* __restrict__ Z2T, const float* __restrict__ GT2T,
    const float* __restrict__ GY, const float* __restrict__ Wm1,
    const float* __restrict__ Wm2, float* __restrict__ forces) {
    __shared__ float w1[NB * H];
    __shared__ alignas(16) float w2t[H * H];   // [k][j]
    int tid = threadIdx.x;
    for (int i = tid; i < NB * H; i += 256) w1[i] = Wm1[i];
    for (int i = tid; i < H * H; i += 256) { int k = i >> 6, j = i & 63; w2t[i] = Wm2[j * H + k]; }
    __syncthreads();
    int e = blockIdx.x * 256 + tid;
    int snd = eidx[e], rcv = eidx[E + e];

    float gt1[H];
#pragma unroll
    for (int j = 0; j < H; ++j) gt1[j] = 0.f;
    for (int k = 0; k < H; ++k) {
        float zz = __bfloat162float(Z2T[(size_t)k * E + e]);
        float g = GT2T[(size_t)k * E + e];
        float sg = sigm(zz);
        float gz2 = g * sg * (1.f + zz * (1.f - sg));
#pragma unroll
        for (int jj = 0; jj < 16; ++jj) {
            float4 w = *reinterpret_cast<const float4*>(&w2t[k * H + jj * 4]);
            gt1[jj * 4 + 0] += gz2 * w.x;
            gt1[jj * 4 + 1] += gz2 * w.y;
            gt1[jj * 4 + 2] += gz2 * w.z;
            gt1[jj * 4 + 3] += gz2 * w.w;
        }
    }
    float ef[NB];
#pragma unroll
    for (int b = 0; b < NB; ++b) ef[b] = EFt[b * E + e];
    float gef[NB];
#pragma unroll
    for (int b = 0; b < NB; ++b) gef[b] = 0.f;
#pragma unroll
    for (int j = 0; j < H; ++j) {
        float z1 = 0.f;
#pragma unroll
        for (int b = 0; b < NB; ++b) z1 += ef[b] * w1[b * H + j];
        float sg = sigm(z1);
        float gz1 = gt1[j] * sg * (1.f + z1 * (1.f - sg));
#pragma unroll
        for (int b = 0; b < NB; ++b) gef[b] += gz1 * w1[b * H + j];
    }
    float vx = pos[rcv * 3 + 0] - pos[snd * 3 + 0] + shifts[e * 3 + 0];
    float vy = pos[rcv * 3 + 1] - pos[snd * 3 + 1] + shifts[e * 3 + 1];
    float vz = pos[rcv * 3 + 2] - pos[snd * 3 + 2] + shifts[e * 3 + 2];
    float r = sqrtf(vx * vx + vy * vy + vz * vz + 1e-12f);
    float inv = 1.0f / r;
    float x = vx * inv, y = vy * inv, z = vz * inv;
    float ru = r * (1.0f / RMAX);
    float env = 0.f, denv_dr = 0.f;
    if (ru < 1.f) {
        float u2 = ru * ru, u4 = u2 * u2, u5 = u4 * ru, u6 = u5 * ru, u7 = u6 * ru, u8 = u7 * ru;
        env = 1.f - 28.f * u6 + 48.f * u7 - 21.f * u8;
        denv_dr = (-168.f * u5 + 336.f * u6 - 168.f * u7) * (1.0f / RMAX);
    }
    float gr = 0.f;
#pragma unroll
    for (int b = 0; b < NB; ++b) {
        float kb = (b + 1) * (PI_F / RMAX);
        float sb = __sinf(kb * r), cb = __cosf(kb * r);
        float bess = BESS_A * sb * inv;
        float dbess = BESS_A * (kb * cb - sb * inv) * inv;
        gr += gef[b] * (dbess * env + bess * denv_dr);
    }
    float gys[S];
#pragma unroll
    for (int s = 0; s < S; ++s) gys[s] = GY[s * E + e];
    float gx = C1 * gys[1] + C2 * y * gys[4] + C2 * z * gys[7] + C2 * x * gys[8];
    float gy = C1 * gys[2] + C2 * x * gys[4] + C2 * z * gys[5] - C2 * y * gys[8];
    float gz = C1 * gys[3] + C2 * y * gys[5] + 6.f * C3 * z * gys[6] + C2 * x * gys[7];
    float dot = gx * x + gy * y + gz * z;
    float gvx = (gx - dot * x) * inv + gr * x;
    float gvy = (gy - dot * y) * inv + gr * y;
    float gvz = (gz - dot * z) * inv + gr * z;
    atomicAdd(&forces[snd * 3 + 0], gvx);
    atomicAdd(&forces[snd * 3 + 1], gvy);
    atomicAdd(&forces[snd * 3 + 2], gvz);
    atomicAdd(&forces[rcv * 3 + 0], -gvx);
    atomicAdd(&forces[rcv * 3 + 1], -gvy);
    atomicAdd(&forces[rcv * 3 + 2], -gvz);
}

} // namespace

extern "C" void kernel_launch(void* const* d_in, const int* in_sizes, int n_in,
                              void* d_out, int out_size, void* d_ws, size_t ws_size,
                              hipStream_t stream) {
    const float* pos    = (const float*)d_in[0];
    const float* attrs  = (const float*)d_in[1];
    const float* shifts = (const float*)d_in[2];
    const float* ae     = (const float*)d_in[3];
    const float* Wemb   = (const float*)d_in[4];
    const float* Wup    = (const float*)d_in[5];
    const float* Wm1    = (const float*)d_in[6];
    const float* Wm2    = (const float*)d_in[7];
    const float* Wm3    = (const float*)d_in[8];
    const float* Wlin   = (const float*)d_in[9];
    const float* Wskip  = (const float*)d_in[10];
    const float* Wprod  = (const float*)d_in[11];
    const float* Wread  = (const float*)d_in[12];
    const float* scale  = (const float*)d_in[13];
    const float* shiftp = (const float*)d_in[14];
    const int*   eidx   = (const int*)d_in[15];
    const int*   batch  = (const int*)d_in[16];

    float* out       = (float*)d_out;
    float* out_tot   = out;                     // G
    float* out_ne    = out + G;                 // N
    float* out_ie    = out + G + N;             // G
    float* out_F     = out + 2 * G + N;         // N*3
    float* out_feats = out + 2 * G + N + 3 * N; // N*2C

    char* w = (char*)d_ws;
    auto alloc = [&](size_t bytes) { void* p = (void*)w; w += (bytes + 255) & ~(size_t)255; return p; };
    int*   sp     = (int*)alloc((size_t)N * 4);
    float* ne0    = (float*)alloc((size_t)N * 4);
    float* es     = (float*)alloc((size_t)N * 4);
    float* e0g    = (float*)alloc((size_t)G * 4);
    float* ieg    = (float*)alloc((size_t)G * 4);
    float* h0     = (float*)alloc((size_t)N * C * 4);
    float* h1     = (float*)alloc((size_t)N * C * 4);
    float* hu0    = (float*)alloc((size_t)N * C * 4);
    float* hu1    = (float*)alloc((size_t)N * C * 4);
    float* msgb   = (float*)alloc((size_t)N * C * 4);
    float* ghu1   = (float*)alloc((size_t)N * C * 4);
    float* gh1    = (float*)alloc((size_t)N * C * 4);
    float* gms1   = (float*)alloc((size_t)CS * 4);
    float* gskip1 = (float*)alloc((size_t)Z * C * 4);
    int*   cnt    = (int*)alloc((size_t)N * 4);
    int*   rowst  = (int*)alloc((size_t)(N + 1) * 4);
    int*   posb   = (int*)alloc((size_t)N * 4);
    int*   perm   = (int*)alloc((size_t)E * 4);
    float* msum   = (float*)alloc((size_t)N * CS * 4);   // fwd msgsum / bwd gm0
    float* EFt    = (float*)alloc((size_t)NB * E * 4);
    float* Yt     = (float*)alloc((size_t)S * E * 4);
    float* GY     = (float*)alloc((size_t)S * E * 4);
    float* T2E    = (float*)alloc((size_t)E * H * 4);    // edge-major t2
    __hip_bfloat16* Z2T = (__hip_bfloat16*)alloc((size_t)H * E * 2);
    // GT2T aliases T2E: bwd1 (last T2E reader) runs before bwd2 (GT2T writer),
    // and layer-0's mlp_fwd re-fills T2E only after layer-1's mlp_bwd consumed GT2T.
    float* GT2T = T2E;

    hipMemsetAsync(es, 0, (size_t)N * 4, stream);
    hipMemsetAsync(e0g, 0, (size_t)G * 4, stream);
    hipMemsetAsync(ieg, 0, (size_t)G * 4, stream);
    hipMemsetAsync(ghu1, 0, (size_t)N * C * 4, stream);
    hipMemsetAsync(cnt, 0, (size_t)N * 4, stream);
    hipMemsetAsync(out_F, 0, (size_t)N * 3 * 4, stream);

    dim3 b256(256);
    int gn   = (N + 255) / 256;
    int gnc  = (N * C + 255) / 256;
    int gncs = (N * CS + 255) / 256;
    int ge   = E / 256;                 // 1250, exact
    int ge5  = E / 512;                 // 625, exact
    int gg   = N / 16;                  // 1250 gather blocks, exact

    // CSR build (receiver-sorted)
    k_csr_count<<<ge, b256, 0, stream>>>(eidx, cnt);
    k_csr_scan<<<1, 1024, 0, stream>>>(cnt, rowst, posb);
    k_csr_fill<<<ge, b256, 0, stream>>>(eidx, posb, perm);

    k_node_init<<<gn, b256, 0, stream>>>(attrs, ae, Wemb, batch, sp, ne0, h0, e0g);
    k_geom<<<ge, b256, 0, stream>>>(pos, shifts, eidx, Yt, EFt);

    // ---- layer 0 forward ----
    k_matmul_CC<<<gnc, b256, 0, stream>>>(h0, Wup, hu0);
    k_mlp_fwd<<<ge, b256, 0, stream>>>(EFt, Wm1, Wm2, T2E, Z2T);
    k_gather<<<gg, 1024, 0, stream>>>(eidx, rowst, perm, hu0, Wm3, T2E, Yt, msum);
    k_msg<<<gnc, b256, 0, stream>>>(msum, Wlin, msgb);
    k_node_h<1><<<gn, b256, 0, stream>>>(msgb, h0, sp, Wprod, Wskip, Wread, h1, es, out_feats);

    // ---- layer 1 forward ----
    k_matmul_CC<<<gnc, b256, 0, stream>>>(h1, Wup + C * C, hu1);
    k_mlp_fwd<<<ge, b256, 0, stream>>>(EFt, Wm1 + NB * H, Wm2 + H * H, T2E, Z2T);
    k_gather<<<gg, 1024, 0, stream>>>(eidx, rowst, perm, hu1, Wm3 + H * CS, T2E, Yt, msum);
    k_msg<<<gnc, b256, 0, stream>>>(msum, Wlin + CS * C, msgb);
    k_node_h<0><<<gn, b256, 0, stream>>>(msgb, h1, sp, Wprod + C * C, Wskip + Z * C * C,
                                         Wread + C, nullptr, es, out_feats + C);

    // ---- energies ----
    k_finalize<<<gn, b256, 0, stream>>>(ne0, es, scale, shiftp, batch, out_ne, ieg);
    k_graph<<<1, G, 0, stream>>>(e0g, ieg, out_tot, out_ie);

    // ---- backward ----
    k_const1<<<1, 512, 0, stream>>>(Wread + C, Wprod + C * C, Wlin + CS * C,
                                    Wskip + Z * C * C, scale, gms1, gskip1);
    // layer 1 backward: bwd1 reads T2E first, then bwd2 overwrites it (as GT2T)
    k_bwd1<true><<<ge5, 512, 0, stream>>>(eidx, hu1, Wm3 + H * CS, T2E, Yt, gms1, GY, ghu1);
    k_bwd2<true><<<ge5, 512, 0, stream>>>(eidx, hu1, Wm3 + H * CS, Yt, gms1, GT2T);
    k_mlp_bwd<<<ge, b256, 0, stream>>>(pos, shifts, eidx, EFt, Z2T, GT2T, GY,
                                       Wm1 + NB * H, Wm2 + H * H, out_F);
    // chain to layer 0
    k_gh1<<<gnc, b256, 0, stream>>>(Wread, gskip1, sp, ghu1, Wup + C * C, scale, gh1);
    k_gmsg<<<gnc, b256, 0, stream>>>(gh1, Wprod, msgb);
    k_gmsum<<<gncs, b256, 0, stream>>>(msgb, Wlin, msum);   // msum <- gm0 (full overwrite)
    // layer 0 backward (recompute layer-0 t2/z2 first)
    k_mlp_fwd<<<ge, b256, 0, stream>>>(EFt, Wm1, Wm2, T2E, Z2T);
    k_bwd1<false><<<ge5, 512, 0, stream>>>(eidx, hu0, Wm3, T2E, Yt, msum, GY, nullptr);
    k_bwd2<false><<<ge5, 512, 0, stream>>>(eidx, hu0, Wm3, Yt, msum, GT2T);
    k_mlp_bwd<<<ge, b256, 0, stream>>>(pos, shifts, eidx, EFt, Z2T, GT2T, GY, Wm1, Wm2, out_F);

    (void)in_sizes; (void)n_in; (void)out_size; (void)ws_size;
}

// Round 6
// 10915.405 us; speedup vs baseline: 1.7445x; 1.7445x over previous
//
#include <hip/hip_runtime.h>
#include <hip/hip_bf16.h>
#include <math.h>

namespace {

constexpr int N = 20000;
constexpr int E = 320000;
constexpr int C = 32;
constexpr int S = 9;
constexpr int Z = 10;
constexpr int G = 16;
constexpr int NB = 8;
constexpr int H = 64;
constexpr int CS = C * S;          // 288
constexpr float RMAX = 5.0f;
constexpr float PI_F = 3.14159265358979323846f;
constexpr float C1 = 1.7320508075688772f;   // sqrt(3)
constexpr float C2 = 3.8729833462074170f;   // sqrt(15)
constexpr float C3 = 1.1180339887498949f;   // sqrt(5)/2
constexpr float BESS_A = 0.6324555320336759f; // sqrt(2/5)

__device__ __forceinline__ float sigm(float x) { return 1.0f / (1.0f + __expf(-x)); }

// ---------------- node-level kernels ----------------

__global__ void k_node_init(const float* __restrict__ attrs, const float* __restrict__ ae,
                            const float* __restrict__ Wemb, const int* __restrict__ batch,
                            int* __restrict__ sp_out, float* __restrict__ ne0,
                            float* __restrict__ h0, float* __restrict__ e0g) {
    int n = blockIdx.x * blockDim.x + threadIdx.x;
    if (n >= N) return;
    int sp = 0;
#pragma unroll
    for (int z = 0; z < Z; ++z)
        if (attrs[n * Z + z] > 0.5f) sp = z;
    sp_out[n] = sp;
    float e = ae[sp];
    ne0[n] = e;
    atomicAdd(&e0g[batch[n]], e);
#pragma unroll
    for (int c = 0; c < C; ++c) h0[n * C + c] = Wemb[sp * C + c];
}

__global__ void k_matmul_CC(const float* __restrict__ hin, const float* __restrict__ W,
                            float* __restrict__ hout) {
    int t = blockIdx.x * blockDim.x + threadIdx.x;
    if (t >= N * C) return;
    int n = t / C, d = t % C;
    float acc = 0.f;
#pragma unroll
    for (int c = 0; c < C; ++c) acc += hin[n * C + c] * W[c * C + d];
    hout[t] = acc;
}

__global__ void k_msg(const float* __restrict__ msum, const float* __restrict__ Wlin,
                      float* __restrict__ msg) {
    int t = blockIdx.x * blockDim.x + threadIdx.x;
    if (t >= N * C) return;
    int n = t / C, d = t % C;
    float acc = 0.f;
    for (int k = 0; k < CS; ++k) acc += msum[(size_t)n * CS + k] * Wlin[k * C + d];
    msg[t] = acc * (1.0f / 16.0f);
}

template <int WRITE_H>
__global__ void k_node_h(const float* __restrict__ msg, const float* __restrict__ hin,
                         const int* __restrict__ sp_arr, const float* __restrict__ Wprod,
                         const float* __restrict__ Wskip, const float* __restrict__ Wread,
                         float* __restrict__ hout_ws, float* __restrict__ es,
                         float* __restrict__ feats_out) {
    int n = blockIdx.x * blockDim.x + threadIdx.x;
    if (n >= N) return;
    int sp = sp_arr[n];
    float m[C], hi[C];
#pragma unroll
    for (int c = 0; c < C; ++c) { m[c] = msg[n * C + c]; hi[c] = hin[n * C + c]; }
    const float* Wsk = Wskip + (size_t)sp * C * C;
    float esum = 0.f;
    for (int d = 0; d < C; ++d) {
        float acc = 0.f;
#pragma unroll
        for (int c = 0; c < C; ++c) acc += m[c] * Wprod[c * C + d] + hi[c] * Wsk[c * C + d];
        esum += acc * Wread[d];
        if constexpr (WRITE_H) hout_ws[n * C + d] = acc;
        feats_out[(size_t)n * (2 * C) + d] = acc;
    }
    es[n] += esum;
}

__global__ void k_finalize(const float* __restrict__ ne0, const float* __restrict__ es,
                           const float* __restrict__ scale_p, const float* __restrict__ shift_p,
                           const int* __restrict__ batch, float* __restrict__ node_energy_out,
                           float* __restrict__ ieg) {
    int n = blockIdx.x * blockDim.x + threadIdx.x;
    if (n >= N) return;
    float nies = scale_p[0] * es[n] + shift_p[0];
    node_energy_out[n] = ne0[n] + nies;
    atomicAdd(&ieg[batch[n]], nies);
}

__global__ void k_graph(const float* __restrict__ e0g, const float* __restrict__ ieg,
                        float* __restrict__ tot_out, float* __restrict__ inter_out) {
    int g = threadIdx.x;
    if (g < G) { tot_out[g] = e0g[g] + ieg[g]; inter_out[g] = ieg[g]; }
}

__global__ void k_const1(const float* __restrict__ Wr1, const float* __restrict__ Wprod1,
                         const float* __restrict__ Wlin1, const float* __restrict__ Wskip1,
                         const float* __restrict__ scale_p, float* __restrict__ gms1,
                         float* __restrict__ gskip1) {
    int t = threadIdx.x;
    float sc = scale_p[0];
    if (t < CS) {
        float acc = 0.f;
        for (int d = 0; d < C; ++d) {
            float gm = 0.f;
#pragma unroll
            for (int d2 = 0; d2 < C; ++d2) gm += Wr1[d2] * Wprod1[d * C + d2];
            acc += gm * Wlin1[t * C + d];
        }
        gms1[t] = sc * acc * (1.0f / 16.0f);
    }
    if (t < Z * C) {
        int z = t / C, c = t % C;
        float acc = 0.f;
#pragma unroll
        for (int d = 0; d < C; ++d) acc += Wskip1[(z * C + c) * C + d] * Wr1[d];
        gskip1[t] = sc * acc;
    }
}

__global__ void k_gh1(const float* __restrict__ Wr0, const float* __restrict__ gskip1,
                      const int* __restrict__ sp_arr, const float* __restrict__ ghu1,
                      const float* __restrict__ Wup1, const float* __restrict__ scale_p,
                      float* __restrict__ gh1) {
    int t = blockIdx.x * blockDim.x + threadIdx.x;
    if (t >= N * C) return;
    int n = t / C, c = t % C;
    float acc = scale_p[0] * Wr0[c] + gskip1[sp_arr[n] * C + c];
#pragma unroll
    for (int d = 0; d < C; ++d) acc += ghu1[n * C + d] * Wup1[c * C + d];
    gh1[t] = acc;
}

__global__ void k_gmsg(const float* __restrict__ gh, const float* __restrict__ Wprod,
                       float* __restrict__ gmsg) {
    int t = blockIdx.x * blockDim.x + threadIdx.x;
    if (t >= N * C) return;
    int n = t / C, d = t % C;
    float acc = 0.f;
#pragma unroll
    for (int d2 = 0; d2 < C; ++d2) acc += gh[n * C + d2] * Wprod[d * C + d2];
    gmsg[t] = acc;
}

__global__ void k_gmsum(const float* __restrict__ gmsg, const float* __restrict__ Wlin,
                        float* __restrict__ gms) {
    int t = blockIdx.x * blockDim.x + threadIdx.x;
    if (t >= N * CS) return;
    int n = t / CS, k = t % CS;
    float acc = 0.f;
#pragma unroll
    for (int d = 0; d < C; ++d) acc += gmsg[n * C + d] * Wlin[k * C + d];
    gms[t] = acc * (1.0f / 16.0f);
}

// ---------------- CSR build (receiver-sorted) ----------------

__global__ void k_csr_count(const int* __restrict__ eidx, int* __restrict__ cnt) {
    int e = blockIdx.x * 256 + threadIdx.x;
    if (e >= E) return;
    atomicAdd(&cnt[eidx[E + e]], 1);
}

__global__ __launch_bounds__(1024) void k_csr_scan(const int* __restrict__ cnt,
                                                   int* __restrict__ rowstart,
                                                   int* __restrict__ pos) {
    __shared__ int part[1024];
    int t = threadIdx.x;
    const int CHUNK = 20;   // 1024*20 >= N
    int base = t * CHUNK;
    int sum = 0;
    for (int i = 0; i < CHUNK; ++i) {
        int idx = base + i;
        if (idx < N) sum += cnt[idx];
    }
    part[t] = sum;
    __syncthreads();
    for (int off = 1; off < 1024; off <<= 1) {
        int v = (t >= off) ? part[t - off] : 0;
        __syncthreads();
        if (t >= off) part[t] += v;
        __syncthreads();
    }
    int run = (t == 0) ? 0 : part[t - 1];
    for (int i = 0; i < CHUNK; ++i) {
        int idx = base + i;
        if (idx < N) { rowstart[idx] = run; pos[idx] = run; run += cnt[idx]; }
    }
    if (t == 1023) rowstart[N] = run;
}

__global__ void k_csr_fill(const int* __restrict__ eidx, int* __restrict__ pos,
                           int* __restrict__ perm) {
    int e = blockIdx.x * 256 + threadIdx.x;
    if (e >= E) return;
    int slot = atomicAdd(&pos[eidx[E + e]], 1);
    perm[slot] = e;
}

// ---------------- edge pipeline ----------------

__global__ __launch_bounds__(256) void k_geom(
    const float* __restrict__ pos, const float* __restrict__ shifts,
    const int* __restrict__ eidx, float* __restrict__ Yt, float* __restrict__ EFt) {
    int e = blockIdx.x * 256 + threadIdx.x;
    int snd = eidx[e], rcv = eidx[E + e];
    float vx = pos[rcv * 3 + 0] - pos[snd * 3 + 0] + shifts[e * 3 + 0];
    float vy = pos[rcv * 3 + 1] - pos[snd * 3 + 1] + shifts[e * 3 + 1];
    float vz = pos[rcv * 3 + 2] - pos[snd * 3 + 2] + shifts[e * 3 + 2];
    float r = sqrtf(vx * vx + vy * vy + vz * vz + 1e-12f);
    float inv = 1.0f / r;
    float x = vx * inv, y = vy * inv, z = vz * inv;
    Yt[0 * E + e] = 1.f;
    Yt[1 * E + e] = C1 * x;
    Yt[2 * E + e] = C1 * y;
    Yt[3 * E + e] = C1 * z;
    Yt[4 * E + e] = C2 * x * y;
    Yt[5 * E + e] = C2 * y * z;
    Yt[6 * E + e] = C3 * (3.f * z * z - 1.f);
    Yt[7 * E + e] = C2 * x * z;
    Yt[8 * E + e] = 0.5f * C2 * (x * x - y * y);
    float ru = r * (1.0f / RMAX);
    float env = 0.f;
    if (ru < 1.f) {
        float u2 = ru * ru, u4 = u2 * u2, u6 = u4 * u2, u7 = u6 * ru, u8 = u7 * ru;
        env = 1.f - 28.f * u6 + 48.f * u7 - 21.f * u8;
    }
#pragma unroll
    for (int b = 0; b < NB; ++b) {
        float kb = (b + 1) * (PI_F / RMAX);
        EFt[b * E + e] = BESS_A * __sinf(kb * r) * inv * env;
    }
}

// T2E (E x H edge-major, float4 stores), Z2^T (H x E k-major, bf16 pre-activation)
__global__ __launch_bounds__(256) void k_mlp_fwd(
    const float* __restrict__ EFt, const float* __restrict__ Wm1,
    const float* __restrict__ Wm2, float* __restrict__ T2E,
    __hip_bfloat16* __restrict__ Z2T) {
    __shared__ float w1[NB * H];
    __shared__ alignas(16) float w2t[H * H];   // transposed: [k][j]
    int tid = threadIdx.x;
    for (int i = tid; i < NB * H; i += 256) w1[i] = Wm1[i];
    for (int i = tid; i < H * H; i += 256) { int k = i >> 6, j = i & 63; w2t[i] = Wm2[j * H + k]; }
    __syncthreads();
    int e = blockIdx.x * 256 + tid;
    float ef[NB];
#pragma unroll
    for (int b = 0; b < NB; ++b) ef[b] = EFt[b * E + e];
    float t1[H];
#pragma unroll
    for (int j = 0; j < H; ++j) {
        float zz = 0.f;
#pragma unroll
        for (int b = 0; b < NB; ++b) zz += ef[b] * w1[b * H + j];
        t1[j] = zz * sigm(zz);
    }
    for (int k4 = 0; k4 < H / 4; ++k4) {
        float o[4];
#pragma unroll
        for (int kk = 0; kk < 4; ++kk) {
            int k = k4 * 4 + kk;
            float s0 = 0.f, s1 = 0.f, s2 = 0.f, s3 = 0.f;
#pragma unroll
            for (int jj = 0; jj < 16; ++jj) {
                float4 w = *reinterpret_cast<const float4*>(&w2t[k * H + jj * 4]);
                s0 += t1[jj * 4 + 0] * w.x;
                s1 += t1[jj * 4 + 1] * w.y;
                s2 += t1[jj * 4 + 2] * w.z;
                s3 += t1[jj * 4 + 3] * w.w;
            }
            float zz = (s0 + s1) + (s2 + s3);
            Z2T[(size_t)k * E + e] = __float2bfloat16(zz);
            o[kk] = zz * sigm(zz);
        }
        *reinterpret_cast<float4*>(&T2E[(size_t)e * H + k4 * 4]) =
            make_float4(o[0], o[1], o[2], o[3]);
    }
}

// gather: wave per receiver node; msum[n,cs] = sum_{e in in(n)} hu[snd,c]*Y[s]*(t2 . W3[:,cs])
// 512 threads (8 waves/nodes per block): avoids the 1024-thread 64-VGPR cap -> no scratch spills.
__global__ __launch_bounds__(512) void k_gather(
    const int* __restrict__ eidx, const int* __restrict__ rowstart,
    const int* __restrict__ perm, const float* __restrict__ hu,
    const float* __restrict__ Wm3, const float* __restrict__ T2E,
    const float* __restrict__ Yt, float* __restrict__ msum) {
    __shared__ float w3[H * CS];   // 73.7 KB, native Wm3 layout [k][cs]
    int tid = threadIdx.x;
    for (int i = tid; i < H * CS; i += 512) w3[i] = Wm3[i];
    __syncthreads();
    int wave = tid >> 6, lane = tid & 63;
    int n = blockIdx.x * 8 + wave;      // 2500 blocks * 8 waves = 20000 exact
    bool has4 = lane < 32;
    int cs4m = has4 ? lane + 256 : lane;
    const int ci0 = lane / 9,         si0 = lane % 9;
    const int ci1 = (lane + 64) / 9,  si1 = (lane + 64) % 9;
    const int ci2 = (lane + 128) / 9, si2 = (lane + 128) % 9;
    const int ci3 = (lane + 192) / 9, si3 = (lane + 192) % 9;
    const int ci4 = cs4m / 9,         si4 = cs4m % 9;
    float acc0 = 0.f, acc1 = 0.f, acc2 = 0.f, acc3 = 0.f, acc4 = 0.f;
    int i0 = rowstart[n], i1 = rowstart[n + 1];
    for (int idx = i0; idx < i1; ++idx) {
        int e = perm[idx];
        int snd = eidx[e];
        float t2l = T2E[(size_t)e * H + lane];
        float yv0 = Yt[si0 * E + e], yv1 = Yt[si1 * E + e], yv2 = Yt[si2 * E + e],
              yv3 = Yt[si3 * E + e], yv4 = Yt[si4 * E + e];
        float hv0 = hu[snd * C + ci0], hv1 = hu[snd * C + ci1], hv2 = hu[snd * C + ci2],
              hv3 = hu[snd * C + ci3], hv4 = hu[snd * C + ci4];
        float d0 = 0.f, d1 = 0.f, d2 = 0.f, d3 = 0.f, d4 = 0.f;
#pragma unroll
        for (int k = 0; k < H; ++k) {
            float tv = __shfl(t2l, k, 64);
            d0 += tv * w3[k * CS + lane];
            d1 += tv * w3[k * CS + lane + 64];
            d2 += tv * w3[k * CS + lane + 128];
            d3 += tv * w3[k * CS + lane + 192];
            d4 += tv * w3[k * CS + cs4m];
        }
        acc0 += hv0 * yv0 * d0;
        acc1 += hv1 * yv1 * d1;
        acc2 += hv2 * yv2 * d2;
        acc3 += hv3 * yv3 * d3;
        acc4 += hv4 * yv4 * d4;
    }
    float* mrow = msum + (size_t)n * CS;
    mrow[lane] = acc0;
    mrow[lane + 64] = acc1;
    mrow[lane + 128] = acc2;
    mrow[lane + 192] = acc3;
    if (has4) mrow[lane + 256] = acc4;
}

// stage one 16-channel slice of Wm3 into LDS [cc][k][12]
__device__ __forceinline__ void stage_w3_half(float* w3t, const float* __restrict__ Wm3,
                                              int half, int tid) {
    for (int i = tid; i < 16 * H * S; i += 512) {
        int cc = i / (H * S), rem = i % (H * S), k = rem / S, s = rem % S;
        w3t[(cc * H + k) * 12 + s] = Wm3[k * CS + (half * 16 + cc) * S + s];
    }
}

// bwd part 1: recompute tpw; gY[s] = sum_c gm*hu*tpw; (L1) ghu[snd,c] += sum_s gm*Y*tpw
template <bool L1>
__global__ __launch_bounds__(512) void k_bwd1(
    const int* __restrict__ eidx, const float* __restrict__ hu,
    const float* __restrict__ Wm3, const float* __restrict__ T2E,
    const float* __restrict__ Yt, const float* __restrict__ gm,
    float* __restrict__ GY, float* __restrict__ ghu) {
    __shared__ alignas(16) float w3t[16 * H * 12];
    int tid = threadIdx.x;
    int e = blockIdx.x * 512 + tid;
    int snd = eidx[e], rcv = eidx[E + e];
    float t2r[H];
#pragma unroll
    for (int k4 = 0; k4 < H / 4; ++k4) {
        float4 v = *reinterpret_cast<const float4*>(&T2E[(size_t)e * H + k4 * 4]);
        t2r[k4 * 4 + 0] = v.x; t2r[k4 * 4 + 1] = v.y;
        t2r[k4 * 4 + 2] = v.z; t2r[k4 * 4 + 3] = v.w;
    }
    float yr[S];
#pragma unroll
    for (int s = 0; s < S; ++s) yr[s] = Yt[s * E + e];
    float gY[S];
#pragma unroll
    for (int s = 0; s < S; ++s) gY[s] = 0.f;
    for (int half = 0; half < 2; ++half) {
        __syncthreads();
        stage_w3_half(w3t, Wm3, half, tid);
        __syncthreads();
        for (int cc = 0; cc < 16; ++cc) {
            int c = half * 16 + cc;
            float hc = hu[snd * C + c];
            const float* gmc = L1 ? (gm + c * S) : (gm + (size_t)rcv * CS + c * S);
            float a[S];
#pragma unroll
            for (int s = 0; s < S; ++s) a[s] = 0.f;
            const float* w3c = &w3t[cc * H * 12];
#pragma unroll
            for (int k = 0; k < H; ++k) {
                float4 wa = *reinterpret_cast<const float4*>(w3c + k * 12);
                float4 wb = *reinterpret_cast<const float4*>(w3c + k * 12 + 4);
                float w8 = w3c[k * 12 + 8];
                float tv = t2r[k];
                a[0] += tv * wa.x; a[1] += tv * wa.y; a[2] += tv * wa.z; a[3] += tv * wa.w;
                a[4] += tv * wb.x; a[5] += tv * wb.y; a[6] += tv * wb.z; a[7] += tv * wb.w;
                a[8] += tv * w8;
            }
            float ghc = 0.f;
#pragma unroll
            for (int s = 0; s < S; ++s) {
                float gmv = gmc[s];
                gY[s] += gmv * hc * a[s];
                if (L1) ghc += gmv * yr[s] * a[s];
            }
            if (L1) atomicAdd(&ghu[snd * C + c], ghc);
        }
    }
#pragma unroll
    for (int s = 0; s < S; ++s) GY[s * E + e] = gY[s];
}

// bwd part 2: gt2[k] = sum_{c,s} (gm*hu*Y)[c,s] * Wm3[k,c,s]  -> GT2^T (H x E)
template <bool L1>
__global__ __launch_bounds__(512) void k_bwd2(
    const int* __restrict__ eidx, const float* __restrict__ hu,
    const float* __restrict__ Wm3, const float* __restrict__ Yt,
    const float* __restrict__ gm, float* __restrict__ GT2T) {
    __shared__ alignas(16) float w3t[16 * H * 12];
    int tid = threadIdx.x;
    int e = blockIdx.x * 512 + tid;
    int snd = eidx[e], rcv = eidx[E + e];
    float yr[S];
#pragma unroll
    for (int s = 0; s < S; ++s) yr[s] = Yt[s * E + e];
    float gt2[H];
#pragma unroll
    for (int k = 0; k < H; ++k) gt2[k] = 0.f;
    for (int half = 0; half < 2; ++half) {
        __syncthreads();
        stage_w3_half(w3t, Wm3, half, tid);
        __syncthreads();
        for (int cc = 0; cc < 16; ++cc) {
            int c = half * 16 + cc;
            float hc = hu[snd * C + c];
            const float* gmc = L1 ? (gm + c * S) : (gm + (size_t)rcv * CS + c * S);
            float gp[S];
#pragma unroll
            for (int s = 0; s < S; ++s) gp[s] = gmc[s] * hc * yr[s];
            const float* w3c = &w3t[cc * H * 12];
#pragma unroll
            for (int k = 0; k < H; ++k) {
                float4 wa = *reinterpret_cast<const float4*>(w3c + k * 12);
                float4 wb = *reinterpret_cast<const float4*>(w3c + k * 12 + 4);
                float w8 = w3c[k * 12 + 8];
                gt2[k] += gp[0] * wa.x + gp[1] * wa.y + gp[2] * wa.z + gp[3] * wa.w
                        + gp[4] * wb.x + gp[5] * wb.y + gp[6] * wb.z + gp[7] * wb.w
                        + gp[8] * w8;
            }
        }
    }
#pragma unroll
    for (int k = 0; k < H; ++k) GT2T[(size_t)k * E + e] = gt2[k];
}

// bwd MLP (streaming, via stored Z2) + geometry backward + force atomics
__global__ __launch_bounds__(256) void k_mlp_bwd(
    const float* __restrict__ pos, const float* __restrict__ shifts,
    const int* __restrict__ eidx, const float* __restrict__ EFt,
    const __hip_bfloat16* __restrict__ Z2T, const float* __restrict__ GT2T,
    const float* __restrict__ GY, const float* __restrict__ Wm1,
    const float* __restrict__ Wm2, float* __restrict__ forces) {
    __shared__ float w1[NB * H];
    __shared__ alignas(16) float w2t[H * H];   // [k][j]
    int tid = threadIdx.x;
    for (int i = tid; i < NB * H; i += 256) w1[i] = Wm1[i];
    for (int i = tid; i < H * H; i += 256) { int k = i >> 6, j = i & 63; w2t[i] = Wm2[j * H + k]; }
    __syncthreads();
    int e = blockIdx.x * 256 + tid;
    int snd = eidx[e], rcv = eidx[E + e];

    float gt1[H];
#pragma unroll
    for (int j = 0; j < H; ++j) gt1[j] = 0.f;
    for (int k = 0; k < H; ++k) {
        float zz = __bfloat162float(Z2T[(size_t)k * E + e]);
        float g = GT2T[(size_t)k * E + e];
        float sg = sigm(zz);
        float gz2 = g * sg * (1.f + zz * (1.f - sg));
#pragma unroll
        for (int jj = 0; jj < 16; ++jj) {
            float4 w = *reinterpret_cast<const float4*>(&w2t[k * H + jj * 4]);
            gt1[jj * 4 + 0] += gz2 * w.x;
            gt1[jj * 4 + 1] += gz2 * w.y;
            gt1[jj * 4 + 2] += gz2 * w.z;
            gt1[jj * 4 + 3] += gz2 * w.w;
        }
    }
    float ef[NB];
#pragma unroll
    for (int b = 0; b < NB; ++b) ef[b] = EFt[b * E + e];
    float gef[NB];
#pragma unroll
    for (int b = 0; b < NB; ++b) gef[b] = 0.f;
#pragma unroll
    for (int j = 0; j < H; ++j) {
        float z1 = 0.f;
#pragma unroll
        for (int b = 0; b < NB; ++b) z1 += ef[b] * w1[b * H + j];
        float sg = sigm(z1);
        float gz1 = gt1[j] * sg * (1.f + z1 * (1.f - sg));
#pragma unroll
        for (int b = 0; b < NB; ++b) gef[b] += gz1 * w1[b * H + j];
    }
    float vx = pos[rcv * 3 + 0] - pos[snd * 3 + 0] + shifts[e * 3 + 0];
    float vy = pos[rcv * 3 + 1] - pos[snd * 3 + 1] + shifts[e * 3 + 1];
    float vz = pos[rcv * 3 + 2] - pos[snd * 3 + 2] + shifts[e * 3 + 2];
    float r = sqrtf(vx * vx + vy * vy + vz * vz + 1e-12f);
    float inv = 1.0f / r;
    float x = vx * inv, y = vy * inv, z = vz * inv;
    float ru = r * (1.0f / RMAX);
    float env = 0.f, denv_dr = 0.f;
    if (ru < 1.f) {
        float u2 = ru * ru, u4 = u2 * u2, u5 = u4 * ru, u6 = u5 * ru, u7 = u6 * ru, u8 = u7 * ru;
        env = 1.f - 28.f * u6 + 48.f * u7 - 21.f * u8;
        denv_dr = (-168.f * u5 + 336.f * u6 - 168.f * u7) * (1.0f / RMAX);
    }
    float gr = 0.f;
#pragma unroll
    for (int b = 0; b < NB; ++b) {
        float kb = (b + 1) * (PI_F / RMAX);
        float sb = __sinf(kb * r), cb = __cosf(kb * r);
        float bess = BESS_A * sb * inv;
        float dbess = BESS_A * (kb * cb - sb * inv) * inv;
        gr += gef[b] * (dbess * env + bess * denv_dr);
    }
    float gys[S];
#pragma unroll
    for (int s = 0; s < S; ++s) gys[s] = GY[s * E + e];
    float gx = C1 * gys[1] + C2 * y * gys[4] + C2 * z * gys[7] + C2 * x * gys[8];
    float gy = C1 * gys[2] + C2 * x * gys[4] + C2 * z * gys[5] - C2 * y * gys[8];
    float gz = C1 * gys[3] + C2 * y * gys[5] + 6.f * C3 * z * gys[6] + C2 * x * gys[7];
    float dot = gx * x + gy * y + gz * z;
    float gvx = (gx - dot * x) * inv + gr * x;
    float gvy = (gy - dot * y) * inv + gr * y;
    float gvz = (gz - dot * z) * inv + gr * z;
    atomicAdd(&forces[snd * 3 + 0], gvx);
    atomicAdd(&forces[snd * 3 + 1], gvy);
    atomicAdd(&forces[snd * 3 + 2], gvz);
    atomicAdd(&forces[rcv * 3 + 0], -gvx);
    atomicAdd(&forces[rcv * 3 + 1], -gvy);
    atomicAdd(&forces[rcv * 3 + 2], -gvz);
}

} // namespace

extern "C" void kernel_launch(void* const* d_in, const int* in_sizes, int n_in,
                              void* d_out, int out_size, void* d_ws, size_t ws_size,
                              hipStream_t stream) {
    const float* pos    = (const float*)d_in[0];
    const float* attrs  = (const float*)d_in[1];
    const float* shifts = (const float*)d_in[2];
    const float* ae     = (const float*)d_in[3];
    const float* Wemb   = (const float*)d_in[4];
    const float* Wup    = (const float*)d_in[5];
    const float* Wm1    = (const float*)d_in[6];
    const float* Wm2    = (const float*)d_in[7];
    const float* Wm3    = (const float*)d_in[8];
    const float* Wlin   = (const float*)d_in[9];
    const float* Wskip  = (const float*)d_in[10];
    const float* Wprod  = (const float*)d_in[11];
    const float* Wread  = (const float*)d_in[12];
    const float* scale  = (const float*)d_in[13];
    const float* shiftp = (const float*)d_in[14];
    const int*   eidx   = (const int*)d_in[15];
    const int*   batch  = (const int*)d_in[16];

    float* out       = (float*)d_out;
    float* out_tot   = out;                     // G
    float* out_ne    = out + G;                 // N
    float* out_ie    = out + G + N;             // G
    float* out_F     = out + 2 * G + N;         // N*3
    float* out_feats = out + 2 * G + N + 3 * N; // N*2C

    char* w = (char*)d_ws;
    auto alloc = [&](size_t bytes) { void* p = (void*)w; w += (bytes + 255) & ~(size_t)255; return p; };
    int*   sp     = (int*)alloc((size_t)N * 4);
    float* ne0    = (float*)alloc((size_t)N * 4);
    float* es     = (float*)alloc((size_t)N * 4);
    float* e0g    = (float*)alloc((size_t)G * 4);
    float* ieg    = (float*)alloc((size_t)G * 4);
    float* h0     = (float*)alloc((size_t)N * C * 4);
    float* h1     = (float*)alloc((size_t)N * C * 4);
    float* hu0    = (float*)alloc((size_t)N * C * 4);
    float* hu1    = (float*)alloc((size_t)N * C * 4);
    float* msgb   = (float*)alloc((size_t)N * C * 4);
    float* ghu1   = (float*)alloc((size_t)N * C * 4);
    float* gh1    = (float*)alloc((size_t)N * C * 4);
    float* gms1   = (float*)alloc((size_t)CS * 4);
    float* gskip1 = (float*)alloc((size_t)Z * C * 4);
    int*   cnt    = (int*)alloc((size_t)N * 4);
    int*   rowst  = (int*)alloc((size_t)(N + 1) * 4);
    int*   posb   = (int*)alloc((size_t)N * 4);
    int*   perm   = (int*)alloc((size_t)E * 4);
    float* msum   = (float*)alloc((size_t)N * CS * 4);   // fwd msgsum / bwd gm0
    float* EFt    = (float*)alloc((size_t)NB * E * 4);
    float* Yt     = (float*)alloc((size_t)S * E * 4);
    float* GY     = (float*)alloc((size_t)S * E * 4);
    float* T2E    = (float*)alloc((size_t)E * H * 4);    // edge-major t2
    __hip_bfloat16* Z2T = (__hip_bfloat16*)alloc((size_t)H * E * 2);
    // GT2T aliases T2E: bwd1 (last T2E reader) runs before bwd2 (GT2T writer),
    // and layer-0's mlp_fwd re-fills T2E only after layer-1's mlp_bwd consumed GT2T.
    float* GT2T = T2E;

    hipMemsetAsync(es, 0, (size_t)N * 4, stream);
    hipMemsetAsync(e0g, 0, (size_t)G * 4, stream);
    hipMemsetAsync(ieg, 0, (size_t)G * 4, stream);
    hipMemsetAsync(ghu1, 0, (size_t)N * C * 4, stream);
    hipMemsetAsync(cnt, 0, (size_t)N * 4, stream);
    hipMemsetAsync(out_F, 0, (size_t)N * 3 * 4, stream);

    dim3 b256(256);
    int gn   = (N + 255) / 256;
    int gnc  = (N * C + 255) / 256;
    int gncs = (N * CS + 255) / 256;
    int ge   = E / 256;                 // 1250, exact
    int ge5  = E / 512;                 // 625, exact
    int gg   = N / 8;                   // 2500 gather blocks, exact

    // CSR build (receiver-sorted)
    k_csr_count<<<ge, b256, 0, stream>>>(eidx, cnt);
    k_csr_scan<<<1, 1024, 0, stream>>>(cnt, rowst, posb);
    k_csr_fill<<<ge, b256, 0, stream>>>(eidx, posb, perm);

    k_node_init<<<gn, b256, 0, stream>>>(attrs, ae, Wemb, batch, sp, ne0, h0, e0g);
    k_geom<<<ge, b256, 0, stream>>>(pos, shifts, eidx, Yt, EFt);

    // ---- layer 0 forward ----
    k_matmul_CC<<<gnc, b256, 0, stream>>>(h0, Wup, hu0);
    k_mlp_fwd<<<ge, b256, 0, stream>>>(EFt, Wm1, Wm2, T2E, Z2T);
    k_gather<<<gg, 512, 0, stream>>>(eidx, rowst, perm, hu0, Wm3, T2E, Yt, msum);
    k_msg<<<gnc, b256, 0, stream>>>(msum, Wlin, msgb);
    k_node_h<1><<<gn, b256, 0, stream>>>(msgb, h0, sp, Wprod, Wskip, Wread, h1, es, out_feats);

    // ---- layer 1 forward ----
    k_matmul_CC<<<gnc, b256, 0, stream>>>(h1, Wup + C * C, hu1);
    k_mlp_fwd<<<ge, b256, 0, stream>>>(EFt, Wm1 + NB * H, Wm2 + H * H, T2E, Z2T);
    k_gather<<<gg, 512, 0, stream>>>(eidx, rowst, perm, hu1, Wm3 + H * CS, T2E, Yt, msum);
    k_msg<<<gnc, b256, 0, stream>>>(msum, Wlin + CS * C, msgb);
    k_node_h<0><<<gn, b256, 0, stream>>>(msgb, h1, sp, Wprod + C * C, Wskip + Z * C * C,
                                         Wread + C, nullptr, es, out_feats + C);

    // ---- energies ----
    k_finalize<<<gn, b256, 0, stream>>>(ne0, es, scale, shiftp, batch, out_ne, ieg);
    k_graph<<<1, G, 0, stream>>>(e0g, ieg, out_tot, out_ie);

    // ---- backward ----
    k_const1<<<1, 512, 0, stream>>>(Wread + C, Wprod + C * C, Wlin + CS * C,
                                    Wskip + Z * C * C, scale, gms1, gskip1);
    // layer 1 backward: bwd1 reads T2E first, then bwd2 overwrites it (as GT2T)
    k_bwd1<true><<<ge5, 512, 0, stream>>>(eidx, hu1, Wm3 + H * CS, T2E, Yt, gms1, GY, ghu1);
    k_bwd2<true><<<ge5, 512, 0, stream>>>(eidx, hu1, Wm3 + H * CS, Yt, gms1, GT2T);
    k_mlp_bwd<<<ge, b256, 0, stream>>>(pos, shifts, eidx, EFt, Z2T, GT2T, GY,
                                       Wm1 + NB * H, Wm2 + H * H, out_F);
    // chain to layer 0
    k_gh1<<<gnc, b256, 0, stream>>>(Wread, gskip1, sp, ghu1, Wup + C * C, scale, gh1);
    k_gmsg<<<gnc, b256, 0, stream>>>(gh1, Wprod, msgb);
    k_gmsum<<<gncs, b256, 0, stream>>>(msgb, Wlin, msum);   // msum <- gm0 (full overwrite)
    // layer 0 backward (recompute layer-0 t2/z2 first)
    k_mlp_fwd<<<ge, b256, 0, stream>>>(EFt, Wm1, Wm2, T2E, Z2T);
    k_bwd1<false><<<ge5, 512, 0, stream>>>(eidx, hu0, Wm3, T2E, Yt, msum, GY, nullptr);
    k_bwd2<false><<<ge5, 512, 0, stream>>>(eidx, hu0, Wm3, Yt, msum, GT2T);
    k_mlp_bwd<<<ge, b256, 0, stream>>>(pos, shifts, eidx, EFt, Z2T, GT2T, GY, Wm1, Wm2, out_F);

    (void)in_sizes; (void)n_in; (void)out_size; (void)ws_size;
}